// Round 8
// baseline (131.586 us; speedup 1.0000x reference)
//
#include <hip/hip_runtime.h>

// Problem constants: B=16 batches, A=5 agents, C=512 channels, H=W=16.
#define NB 16
#define NA 5
#define NC 512
#define HW 256
#define NCHG 64                  // 8-channel groups
#define NBLK (NB * NCHG)         // 1024 blocks = (batch, 8ch-group)

typedef float f4 __attribute__((ext_vector_type(4)));
typedef _Float16 h8 __attribute__((ext_vector_type(8)));   // 16 B = ds b128

static __device__ __forceinline__ h8 splat8(float v) {
    const _Float16 h = (_Float16)v;
    h8 r = {h, h, h, h, h, h, h, h};
    return r;
}

// Block = (batch b, 8-ch group). Phase 1: stage ALL n agent slabs once
// (px-major fp16 h8; f4 global loads + in-lane transpose). ONE barrier.
// Phase 2: 4 waves independently sweep 20 strips (5 agents x 4 px-quarters);
// per strip: exact-f32 residual + (n-1) collapsed 16-tap pair gathers with
// fully batched addresses (16 ds_read_b128 in flight) and channel-amortized
// weights. No inter-wave coupling after the single barrier.
__global__ __launch_bounds__(256) void fafmimo_strip_kernel(
    const float* __restrict__ feat,   // [A*B][C][256], feat[a*B+b] = local[b][a]
    const float* __restrict__ trans,  // [B][A][A][4][4]
    const int*   __restrict__ numa,   // [B][A], use [:,0]
    float*       __restrict__ out)    // [A*B][C][256]
{
    __shared__ h8 slab[NA][HW];       // 20 KiB, [agent][px], 8ch interleaved

    const int blk = blockIdx.x;
    const int b   = blk & (NB - 1);   // batch fastest: mixes heavy/light blocks
    const int g   = blk >> 4;
    const int c0  = g << 3;
    const int tid = threadIdx.x;
    const int w   = tid >> 6;         // wave 0..3
    const int l   = tid & 63;         // lane
    const int n   = numa[b * NA];     // block-uniform

    // ---- phase 1: stage slabs (wave w handles agents w, w+4) ----
    if (n > 1) {
        for (int j = w; j < n; j += 4) {
            const float* src = feat + ((size_t)(j * NB + b) * NC + c0) * HW + 4 * l;
            f4 t[8];
#pragma unroll
            for (int k = 0; k < 8; ++k) t[k] = *(const f4*)(src + k * HW);
#pragma unroll
            for (int m = 0; m < 4; ++m) {
                h8 hv;
#pragma unroll
                for (int k = 0; k < 8; ++k) hv[k] = (_Float16)t[k][m];
                slab[j][4 * l + m] = hv;
            }
        }
    }
    __syncthreads();                  // the ONLY barrier in the kernel

    // ---- phase 2: independent strips ----
    for (int s = w; s < 20; s += 4) {
        const int i  = s >> 2;        // output agent
        const int q  = s & 3;         // px quarter
        const int px = (q << 6) + l;
        const int x  = px & 15, y = px >> 4;
        const size_t base = ((size_t)(i * NB + b) * NC + c0) * HW + px;

        // residual: exact f32 (issued before the gather, consumed after)
        float own[8];
#pragma unroll
        for (int k = 0; k < 8; ++k) own[k] = feat[base + k * HW];

        h8 pacc = splat8(0.0f);
        if (i < n && n > 1) {
            for (int j = 0; j < n; ++j) {
                if (j == i) continue;

                const float* tb = trans + (size_t)(((b * NA) + i) * NA + j) * 16;
                const f4 row0 = *(const f4*)tb;        // r00 r01 _ tx
                const f4 row1 = *(const f4*)(tb + 4);  // r10 r11 _ ty
                const float r00 = row0.x, r01 = row0.y;
                const float r10 = row1.x, r11 = row1.y;

                // ---- batched tap table: 16 (addr, weight) first ----
                int   ta[16];
                float wa[16];
                {
                    const float dx = 0.25f * row0.w;
                    const float dy = -0.25f * row1.w;
                    const float fdx = floorf(dx), fdy = floorf(dy);
                    const float tx1 = dx - fdx, tx0 = 1.0f - tx1;
                    const float ty1 = dy - fdy, ty0 = 1.0f - ty1;
                    const int ox = x + (int)fdx;
                    const int oy = y + (int)fdy;
                    const float fox = (float)ox - 7.5f;
                    const float foy = (float)oy - 7.5f;
                    const float bxr = r00 * fox + r01 * foy + 7.5f;
                    const float byr = r10 * fox + r11 * foy + 7.5f;
                    int t = 0;
#pragma unroll
                    for (int sy = 0; sy < 2; ++sy)
#pragma unroll
                    for (int sx = 0; sx < 2; ++sx) {
                        const int tox = ox + sx, toy = oy + sy;
                        const bool in2 = (tox >= 0) && (tox < 16) && (toy >= 0) && (toy < 16);
                        const float ws = in2 ? (sx ? tx1 : tx0) * (sy ? ty1 : ty0) : 0.0f;
                        const float cx = bxr + (float)sx * r00 + (float)sy * r01;
                        const float cy = byr + (float)sx * r10 + (float)sy * r11;
                        const float fx0 = floorf(cx), fy0 = floorf(cy);
                        const float wx1 = cx - fx0, wy1 = cy - fy0;
                        const int ix0 = (int)fx0, iy0 = (int)fy0;
                        const float mx0 = (ix0 >= 0 && ix0 < 16) ? 1.0f - wx1 : 0.0f;
                        const float mx1 = (ix0 + 1 >= 0 && ix0 + 1 < 16) ? wx1 : 0.0f;
                        const float my0 = ((iy0 >= 0 && iy0 < 16) ? 1.0f - wy1 : 0.0f) * ws;
                        const float my1 = ((iy0 + 1 >= 0 && iy0 + 1 < 16) ? wy1 : 0.0f) * ws;
                        const int cx0 = min(max(ix0, 0), 15), cx1 = min(max(ix0 + 1, 0), 15);
                        const int cy0 = min(max(iy0, 0), 15), cy1 = min(max(iy0 + 1, 0), 15);
                        ta[t] = cy0 * 16 + cx0; wa[t++] = mx0 * my0;
                        ta[t] = cy0 * 16 + cx1; wa[t++] = mx1 * my0;
                        ta[t] = cy1 * 16 + cx0; wa[t++] = mx0 * my1;
                        ta[t] = cy1 * 16 + cx1; wa[t++] = mx1 * my1;
                    }
                }

                // ---- 16 b128 loads issued back-to-back, then fma tree ----
                const h8* sj = &slab[j][0];
                h8 tv[16];
#pragma unroll
                for (int t = 0; t < 16; ++t) tv[t] = sj[ta[t]];
#pragma unroll
                for (int t = 0; t < 16; ++t) pacc += tv[t] * splat8(wa[t]);
            }
        }

        float* dst = out + base;
#pragma unroll
        for (int k = 0; k < 8; ++k) dst[k * HW] = own[k] + (float)pacc[k];
    }
}

extern "C" void kernel_launch(void* const* d_in, const int* in_sizes, int n_in,
                              void* d_out, int out_size, void* d_ws, size_t ws_size,
                              hipStream_t stream) {
    const float* feat  = (const float*)d_in[0];
    const float* trans = (const float*)d_in[1];
    const int*   numa  = (const int*)d_in[2];
    float* out = (float*)d_out;

    fafmimo_strip_kernel<<<dim3(NBLK), dim3(256), 0, stream>>>(
        feat, trans, numa, out);
}